// Round 3
// baseline (2659.708 us; speedup 1.0000x reference)
//
#include <hip/hip_runtime.h>
#include <cstdint>
#include <cstddef>

// (B, H, D, STEP) = (2048, 512, 256, 64)
constexpr int NB  = 2048;
constexpr int NH  = 512;
constexpr int ND  = 256;
constexpr int NT  = 64;
constexpr int N4H = 2048;

typedef __attribute__((ext_vector_type(8))) __bf16 bf16x8;
typedef __attribute__((ext_vector_type(4))) float  f32x4;

__device__ inline unsigned short f2bf_rne(float f) {
    unsigned u = __builtin_bit_cast(unsigned, f);
    unsigned r = (u + 0x7FFFu + ((u >> 16) & 1u)) >> 16;
    return (unsigned short)r;
}
__device__ inline float bf2f(unsigned short h) {
    unsigned u = ((unsigned)h) << 16;
    return __builtin_bit_cast(float, u);
}

// ---------------- prep: combine weights, split to bf16 hi/lo, reorder Wsum rows,
// init cc from c, zero h. Wsum row reorder: n' = jg*128 + g*32 + c  <-  g*512 + jg*32 + c
__global__ __launch_bounds__(256) void prep_kernel(
    const float* __restrict__ c,   const float* __restrict__ Wih,
    const float* __restrict__ Whh, const float* __restrict__ bih,
    const float* __restrict__ bhh, const float* __restrict__ Whr,
    float* __restrict__ cc, float* __restrict__ bsum,
    unsigned short* __restrict__ WrH,  unsigned short* __restrict__ WrL,
    unsigned short* __restrict__ WhrH, unsigned short* __restrict__ WhrL,
    unsigned short* __restrict__ hH,   unsigned short* __restrict__ hL)
{
    int i = blockIdx.x * 256 + threadIdx.x;        // 0 .. NB*NH-1 (1M)
    cc[i] = c[i];                                  // c is (B,H,1) contiguous
    if (i < N4H) bsum[i] = bih[i] + bhh[i];
    if (i < N4H * ND) {                            // 524288: Wr reorder+split; h zero
        int np = i >> 8, k = i & 255;
        int jg = np >> 7, r = np & 127, g = r >> 5, cu = r & 31;
        int src = (g * NH + jg * 32 + cu) * ND + k;
        float w = Wih[src] + Whh[src];
        unsigned short hi = f2bf_rne(w);
        WrH[i] = hi; WrL[i] = f2bf_rne(w - bf2f(hi));
        hH[i] = 0; hL[i] = 0;                      // NB*ND == N4H*ND
    }
    if (i < ND * NH) {                             // 131072: Whr split ([256][512])
        float w = Whr[i];
        unsigned short hi = f2bf_rne(w);
        WhrH[i] = hi; WhrL[i] = f2bf_rne(w - bf2f(hi));
    }
}

// ---- stage one 128x64-elem bf16 tile into LDS (16KB) via global_load_lds width 16.
// LDS dest: linear, wave-uniform base + lane*16 (HW semantics). Global src: per-lane,
// pre-swizzled (kb ^ ((row&7)<<4)) so that swizzled ds_reads see logical data (rule #21).
__device__ inline void stage_tile(const unsigned short* __restrict__ g,
                                  int row0, int ldgElems, int k0Elems,
                                  char* smem, int ldsOff, int wave, int lane)
{
#pragma unroll
    for (int q = 0; q < 4; ++q) {
        int L   = wave * 4096 + q * 1024 + lane * 16;   // tile-local byte offset
        int row = L >> 7;
        int kb  = L & 127;
        int kbs = kb ^ ((row & 7) << 4);
        const char* src = (const char*)g +
            (size_t)(row0 + row) * (ldgElems * 2) + k0Elems * 2 + kbs;
        char* dst = smem + ldsOff + wave * 4096 + q * 1024;   // wave-uniform
        __builtin_amdgcn_global_load_lds(
            (const __attribute__((address_space(1))) unsigned int*)src,
            (__attribute__((address_space(3))) unsigned int*)dst,
            16, 0, 0);
    }
}

__device__ inline bf16x8 frag_ld(const char* smem, int off, int row, int kb) {
    int kbs = kb ^ ((row & 7) << 4);
    return *(const bf16x8*)(smem + off + row * 128 + kbs);
}

// ---------------- GEMM1 + fused gates: z = h @ WrT (+bias), gates, cc update,
// a = o*tanh(cc) written as bf16 hi/lo. Tile 128(b) x 128(n'), K=256.
__global__ __launch_bounds__(256) void gates_mfma(
    const unsigned short* __restrict__ hH, const unsigned short* __restrict__ hL,
    const unsigned short* __restrict__ WrH, const unsigned short* __restrict__ WrL,
    const float* __restrict__ bsum, float* __restrict__ cc,
    unsigned short* __restrict__ aH, unsigned short* __restrict__ aL)
{
    __shared__ char smem[65536];
    constexpr int AsH = 0, AsL = 16384, BsH = 32768, BsL = 49152;

    const int tid  = threadIdx.x;
    const int lane = tid & 63;
    const int wave = tid >> 6;
    const int wr = wave >> 1, wc = wave & 1;
    const int b0 = blockIdx.x * 128;
    const int n0 = blockIdx.y * 128;

    f32x4 acc[4][4];
#pragma unroll
    for (int mi = 0; mi < 4; ++mi)
#pragma unroll
        for (int ni = 0; ni < 4; ++ni)
            acc[mi][ni] = f32x4{0.f, 0.f, 0.f, 0.f};

    const int lrow = lane & 15;
    const int lk   = (lane >> 4) * 16;    // k-group byte offset (8 elems * 2B)

    for (int ch = 0; ch < 4; ++ch) {
        __syncthreads();                  // staging buffer free of prior readers
        stage_tile(hH,  b0, ND, ch * 64, smem, AsH, wave, lane);
        stage_tile(hL,  b0, ND, ch * 64, smem, AsL, wave, lane);
        stage_tile(WrH, n0, ND, ch * 64, smem, BsH, wave, lane);
        stage_tile(WrL, n0, ND, ch * 64, smem, BsL, wave, lane);
        __syncthreads();                  // compiler drains vmcnt before barrier
#pragma unroll
        for (int kk = 0; kk < 2; ++kk) {
            const int kb = kk * 64 + lk;
            bf16x8 aHf[4], aLf[4], bHf[4], bLf[4];
#pragma unroll
            for (int mi = 0; mi < 4; ++mi) {
                int row = wr * 64 + mi * 16 + lrow;
                aHf[mi] = frag_ld(smem, AsH, row, kb);
                aLf[mi] = frag_ld(smem, AsL, row, kb);
            }
#pragma unroll
            for (int ni = 0; ni < 4; ++ni) {
                int row = wc * 64 + ni * 16 + lrow;
                bHf[ni] = frag_ld(smem, BsH, row, kb);
                bLf[ni] = frag_ld(smem, BsL, row, kb);
            }
#pragma unroll
            for (int mi = 0; mi < 4; ++mi)
#pragma unroll
                for (int ni = 0; ni < 4; ++ni) {
                    acc[mi][ni] = __builtin_amdgcn_mfma_f32_16x16x32_bf16(aHf[mi], bHf[ni], acc[mi][ni], 0, 0, 0);
                    acc[mi][ni] = __builtin_amdgcn_mfma_f32_16x16x32_bf16(aHf[mi], bLf[ni], acc[mi][ni], 0, 0, 0);
                    acc[mi][ni] = __builtin_amdgcn_mfma_f32_16x16x32_bf16(aLf[mi], bHf[ni], acc[mi][ni], 0, 0, 0);
                    acc[mi][ni] = __builtin_amdgcn_mfma_f32_16x16x32_bf16(aLf[mi], bLf[ni], acc[mi][ni], 0, 0, 0);
                }
        }
    }
    __syncthreads();                      // all frag reads done; reuse smem as z
    float (*z)[128] = (float(*)[128])smem;
#pragma unroll
    for (int mi = 0; mi < 4; ++mi)
#pragma unroll
        for (int ni = 0; ni < 4; ++ni)
#pragma unroll
            for (int r = 0; r < 4; ++r) {
                int m = wr * 64 + mi * 16 + (lane >> 4) * 4 + r;
                int n = wc * 64 + ni * 16 + (lane & 15);
                z[m][n] = acc[mi][ni][r];
            }
    __syncthreads();
    // epilogue: n-tile covers 32 h-cols x 4 gates (gate-stride 32 via W reorder)
    const int cu = tid & 31;
    const int rg = tid >> 5;              // 0..7
    const int j  = blockIdx.y * 32 + cu;
    const float bi = bsum[0 * NH + j], bfv = bsum[1 * NH + j];
    const float bg = bsum[2 * NH + j], bo  = bsum[3 * NH + j];
#pragma unroll
    for (int it = 0; it < 16; ++it) {
        int m = rg * 16 + it;
        size_t idx = (size_t)(b0 + m) * NH + j;
        float zi = z[m][cu]      + bi;
        float zf = z[m][32 + cu] + bfv;
        float zg = z[m][64 + cu] + bg;
        float zo = z[m][96 + cu] + bo;
        float iv = 1.f / (1.f + expf(-zi));
        float fv = 1.f / (1.f + expf(-zf));
        float gv = tanhf(zg);
        float ov = 1.f / (1.f + expf(-zo));
        float cv = fv * cc[idx] + iv * gv;
        cc[idx] = cv;
        float av = ov * tanhf(cv);
        unsigned short ah = f2bf_rne(av);
        aH[idx] = ah;
        aL[idx] = f2bf_rne(av - bf2f(ah));
    }
}

// ---------------- GEMM2: h_new = a @ Whr^T. Tile 128(b) x 128(d), K=512.
template <bool STAGED>
__global__ __launch_bounds__(256) void recur_mfma(
    const unsigned short* __restrict__ aH, const unsigned short* __restrict__ aL,
    const unsigned short* __restrict__ WhrHp, const unsigned short* __restrict__ WhrLp,
    unsigned short* __restrict__ hH, unsigned short* __restrict__ hL,
    float* __restrict__ hseq, float* __restrict__ out, int t)
{
    __shared__ char smem[65536];
    constexpr int AsH = 0, AsL = 16384, BsH = 32768, BsL = 49152;

    const int tid  = threadIdx.x;
    const int lane = tid & 63;
    const int wave = tid >> 6;
    const int wr = wave >> 1, wc = wave & 1;
    const int b0 = blockIdx.x * 128;
    const int d0 = blockIdx.y * 128;

    f32x4 acc[4][4];
#pragma unroll
    for (int mi = 0; mi < 4; ++mi)
#pragma unroll
        for (int ni = 0; ni < 4; ++ni)
            acc[mi][ni] = f32x4{0.f, 0.f, 0.f, 0.f};

    const int lrow = lane & 15;
    const int lk   = (lane >> 4) * 16;

    for (int ch = 0; ch < 8; ++ch) {
        __syncthreads();
        stage_tile(aH,    b0, NH, ch * 64, smem, AsH, wave, lane);
        stage_tile(aL,    b0, NH, ch * 64, smem, AsL, wave, lane);
        stage_tile(WhrHp, d0, NH, ch * 64, smem, BsH, wave, lane);
        stage_tile(WhrLp, d0, NH, ch * 64, smem, BsL, wave, lane);
        __syncthreads();
#pragma unroll
        for (int kk = 0; kk < 2; ++kk) {
            const int kb = kk * 64 + lk;
            bf16x8 aHf[4], aLf[4], bHf[4], bLf[4];
#pragma unroll
            for (int mi = 0; mi < 4; ++mi) {
                int row = wr * 64 + mi * 16 + lrow;
                aHf[mi] = frag_ld(smem, AsH, row, kb);
                aLf[mi] = frag_ld(smem, AsL, row, kb);
            }
#pragma unroll
            for (int ni = 0; ni < 4; ++ni) {
                int row = wc * 64 + ni * 16 + lrow;
                bHf[ni] = frag_ld(smem, BsH, row, kb);
                bLf[ni] = frag_ld(smem, BsL, row, kb);
            }
#pragma unroll
            for (int mi = 0; mi < 4; ++mi)
#pragma unroll
                for (int ni = 0; ni < 4; ++ni) {
                    acc[mi][ni] = __builtin_amdgcn_mfma_f32_16x16x32_bf16(aHf[mi], bHf[ni], acc[mi][ni], 0, 0, 0);
                    acc[mi][ni] = __builtin_amdgcn_mfma_f32_16x16x32_bf16(aHf[mi], bLf[ni], acc[mi][ni], 0, 0, 0);
                    acc[mi][ni] = __builtin_amdgcn_mfma_f32_16x16x32_bf16(aLf[mi], bHf[ni], acc[mi][ni], 0, 0, 0);
                    acc[mi][ni] = __builtin_amdgcn_mfma_f32_16x16x32_bf16(aLf[mi], bLf[ni], acc[mi][ni], 0, 0, 0);
                }
        }
    }
    // epilogue straight from accumulators
#pragma unroll
    for (int mi = 0; mi < 4; ++mi)
#pragma unroll
        for (int ni = 0; ni < 4; ++ni)
#pragma unroll
            for (int r = 0; r < 4; ++r) {
                int b = b0 + wr * 64 + mi * 16 + (lane >> 4) * 4 + r;
                int d = d0 + wc * 64 + ni * 16 + (lane & 15);
                float v = acc[mi][ni][r];
                if (STAGED) hseq[((size_t)t * NB + b) * ND + d] = v;
                else        out[((size_t)b * ND + d) * NT + t]  = v;
                size_t hidx = (size_t)b * ND + d;
                unsigned short hh = f2bf_rne(v);
                hH[hidx] = hh;
                hL[hidx] = f2bf_rne(v - bf2f(hh));
            }
}

// ---------------- final transpose: hseq (t,b,d) -> out (b,d,t)
__global__ __launch_bounds__(256) void transpose_kernel(
    const float* __restrict__ hseq, float* __restrict__ out) {
    __shared__ float tile[64][65];
    const int tid = threadIdx.x;
    const int d0  = blockIdx.x * 64;
    const int b   = blockIdx.y;
    const int x   = tid & 63;
    const int y   = tid >> 6;  // 0..3
#pragma unroll
    for (int r = 0; r < 16; ++r) {
        int t = y + r * 4;
        tile[t][x] = hseq[((size_t)t * NB + b) * ND + d0 + x];
    }
    __syncthreads();
#pragma unroll
    for (int r = 0; r < 16; ++r) {
        int d = y + r * 4;
        out[((size_t)b * ND + d0 + d) * NT + x] = tile[x][d];
    }
}

extern "C" void kernel_launch(void* const* d_in, const int* in_sizes, int n_in,
                              void* d_out, int out_size, void* d_ws, size_t ws_size,
                              hipStream_t stream) {
    const float* c   = (const float*)d_in[0];
    const float* Wih = (const float*)d_in[1];
    const float* Whh = (const float*)d_in[2];
    const float* bih = (const float*)d_in[3];
    const float* bhh = (const float*)d_in[4];
    const float* Whr = (const float*)d_in[5];
    float* out = (float*)d_out;

    char* ws = (char*)d_ws;
    size_t off = 0;
    auto alloc = [&](size_t bytes) -> char* {
        char* p = ws + off;
        off = (off + bytes + 255) & ~(size_t)255;
        return p;
    };
    float*          cc    = (float*)alloc((size_t)NB * NH * 4);
    float*          bsum  = (float*)alloc((size_t)N4H * 4);
    unsigned short* WrHp  = (unsigned short*)alloc((size_t)N4H * ND * 2);
    unsigned short* WrLp  = (unsigned short*)alloc((size_t)N4H * ND * 2);
    unsigned short* WhrHp = (unsigned short*)alloc((size_t)ND * NH * 2);
    unsigned short* WhrLp = (unsigned short*)alloc((size_t)ND * NH * 2);
    unsigned short* hH    = (unsigned short*)alloc((size_t)NB * ND * 2);
    unsigned short* hL    = (unsigned short*)alloc((size_t)NB * ND * 2);
    unsigned short* aH    = (unsigned short*)alloc((size_t)NB * NH * 2);
    unsigned short* aL    = (unsigned short*)alloc((size_t)NB * NH * 2);
    size_t hseq_bytes = (size_t)NT * NB * ND * 4;
    float* hseq = (float*)(ws + off);
    const bool staged = (off + hseq_bytes) <= ws_size;

    prep_kernel<<<(NB * NH) / 256, 256, 0, stream>>>(
        c, Wih, Whh, bih, bhh, Whr, cc, bsum, WrHp, WrLp, WhrHp, WhrLp, hH, hL);

    dim3 g1(NB / 128, N4H / 128);  // 16 x 16 = 256 blocks
    dim3 g2(NB / 128, ND / 128);   // 16 x 2  = 32 blocks
    for (int t = 0; t < NT; ++t) {
        gates_mfma<<<g1, 256, 0, stream>>>(hH, hL, WrHp, WrLp, bsum, cc, aH, aL);
        if (staged)
            recur_mfma<true><<<g2, 256, 0, stream>>>(aH, aL, WhrHp, WhrLp,
                                                     hH, hL, hseq, out, t);
        else
            recur_mfma<false><<<g2, 256, 0, stream>>>(aH, aL, WhrHp, WhrLp,
                                                      hH, hL, hseq, out, t);
    }
    if (staged) {
        dim3 gt(ND / 64, NB);
        transpose_kernel<<<gt, 256, 0, stream>>>(hseq, out);
    }
}

// Round 4
// 2009.940 us; speedup vs baseline: 1.3233x; 1.3233x over previous
//
#include <hip/hip_runtime.h>
#include <cstdint>
#include <cstddef>

// (B, H, D, STEP) = (2048, 512, 256, 64)
constexpr int NB  = 2048;
constexpr int NH  = 512;
constexpr int ND  = 256;
constexpr int NT  = 64;
constexpr int N4H = 2048;

typedef __attribute__((ext_vector_type(8))) __bf16 bf16x8;
typedef __attribute__((ext_vector_type(4))) float  f32x4;

__device__ inline unsigned short f2bf_rne(float f) {
    unsigned u = __builtin_bit_cast(unsigned, f);
    unsigned r = (u + 0x7FFFu + ((u >> 16) & 1u)) >> 16;
    return (unsigned short)r;
}
__device__ inline float bf2f(unsigned short h) {
    unsigned u = ((unsigned)h) << 16;
    return __builtin_bit_cast(float, u);
}

// ---------------- prep: combine weights, split to bf16 hi/lo, reorder Wsum rows,
// init cc from c, zero h. Wsum row reorder: n' = jg*128 + g*32 + c  <-  g*512 + jg*32 + c
__global__ __launch_bounds__(256) void prep_kernel(
    const float* __restrict__ c,   const float* __restrict__ Wih,
    const float* __restrict__ Whh, const float* __restrict__ bih,
    const float* __restrict__ bhh, const float* __restrict__ Whr,
    float* __restrict__ cc, float* __restrict__ bsum,
    unsigned short* __restrict__ WrH,  unsigned short* __restrict__ WrL,
    unsigned short* __restrict__ WhrH, unsigned short* __restrict__ WhrL,
    unsigned short* __restrict__ hH,   unsigned short* __restrict__ hL)
{
    int i = blockIdx.x * 256 + threadIdx.x;        // 0 .. NB*NH-1 (1M)
    cc[i] = c[i];                                  // c is (B,H,1) contiguous
    if (i < N4H) bsum[i] = bih[i] + bhh[i];
    if (i < N4H * ND) {                            // 524288: Wr reorder+split; h zero
        int np = i >> 8, k = i & 255;
        int jg = np >> 7, r = np & 127, g = r >> 5, cu = r & 31;
        int src = (g * NH + jg * 32 + cu) * ND + k;
        float w = Wih[src] + Whh[src];
        unsigned short hi = f2bf_rne(w);
        WrH[i] = hi; WrL[i] = f2bf_rne(w - bf2f(hi));
        hH[i] = 0; hL[i] = 0;                      // NB*ND == N4H*ND
    }
    if (i < ND * NH) {                             // 131072: Whr split ([256][512])
        float w = Whr[i];
        unsigned short hi = f2bf_rne(w);
        WhrH[i] = hi; WhrL[i] = f2bf_rne(w - bf2f(hi));
    }
}

// ---- stage one ROWSx64-elem bf16 tile into LDS via global_load_lds width 16.
// LDS dest: linear, wave-uniform base + lane*16 (HW semantics). Global src: per-lane,
// pre-swizzled (kb ^ ((row&7)<<4)) so swizzled ds_reads see logical data (rule #21).
template <int ROWS>
__device__ inline void stage_tile(const unsigned short* __restrict__ g,
                                  int row0, int ldgElems, int k0Elems,
                                  char* smem, int ldsOff, int wave, int lane)
{
    constexpr int QN = ROWS / 32;                       // 1KB per q per wave
#pragma unroll
    for (int q = 0; q < QN; ++q) {
        int L   = wave * (ROWS * 32) + q * 1024 + lane * 16;  // tile-local byte off
        int row = L >> 7;
        int kb  = L & 127;
        int kbs = kb ^ ((row & 7) << 4);
        const char* src = (const char*)g +
            (size_t)(row0 + row) * (ldgElems * 2) + k0Elems * 2 + kbs;
        char* dst = smem + ldsOff + wave * (ROWS * 32) + q * 1024;  // wave-uniform
        __builtin_amdgcn_global_load_lds(
            (const __attribute__((address_space(1))) unsigned int*)src,
            (__attribute__((address_space(3))) unsigned int*)dst,
            16, 0, 0);
    }
}

__device__ inline bf16x8 frag_ld(const char* smem, int off, int row, int kb) {
    int kbs = kb ^ ((row & 7) << 4);
    return *(const bf16x8*)(smem + off + row * 128 + kbs);
}

// ---------------- GEMM1 + fused gates: z = h @ WrT (+bias), gates, cc update,
// a = o*tanh(cc) written as bf16 hi/lo. Tile 128(b) x 128(n'), K=256. 3-term split.
__global__ __launch_bounds__(256) void gates_mfma(
    const unsigned short* __restrict__ hH, const unsigned short* __restrict__ hL,
    const unsigned short* __restrict__ WrH, const unsigned short* __restrict__ WrL,
    const float* __restrict__ bsum, float* __restrict__ cc,
    unsigned short* __restrict__ aH, unsigned short* __restrict__ aL)
{
    __shared__ char smem[65536];
    constexpr int AsH = 0, AsL = 16384, BsH = 32768, BsL = 49152;

    const int tid  = threadIdx.x;
    const int lane = tid & 63;
    const int wave = tid >> 6;
    const int wr = wave >> 1, wc = wave & 1;
    const int b0 = blockIdx.x * 128;
    const int n0 = blockIdx.y * 128;

    f32x4 acc[4][4];
#pragma unroll
    for (int mi = 0; mi < 4; ++mi)
#pragma unroll
        for (int ni = 0; ni < 4; ++ni)
            acc[mi][ni] = f32x4{0.f, 0.f, 0.f, 0.f};

    const int lrow = lane & 15;
    const int lk   = (lane >> 4) * 16;    // k-group byte offset (8 elems * 2B)

    for (int ch = 0; ch < 4; ++ch) {
        __syncthreads();                  // staging buffer free of prior readers
        stage_tile<128>(hH,  b0, ND, ch * 64, smem, AsH, wave, lane);
        stage_tile<128>(hL,  b0, ND, ch * 64, smem, AsL, wave, lane);
        stage_tile<128>(WrH, n0, ND, ch * 64, smem, BsH, wave, lane);
        stage_tile<128>(WrL, n0, ND, ch * 64, smem, BsL, wave, lane);
        __syncthreads();                  // compiler drains vmcnt before barrier
#pragma unroll
        for (int kk = 0; kk < 2; ++kk) {
            const int kb = kk * 64 + lk;
            bf16x8 aHf[4], aLf[4], bHf[4], bLf[4];
#pragma unroll
            for (int mi = 0; mi < 4; ++mi) {
                int row = wr * 64 + mi * 16 + lrow;
                aHf[mi] = frag_ld(smem, AsH, row, kb);
                aLf[mi] = frag_ld(smem, AsL, row, kb);
            }
#pragma unroll
            for (int ni = 0; ni < 4; ++ni) {
                int row = wc * 64 + ni * 16 + lrow;
                bHf[ni] = frag_ld(smem, BsH, row, kb);
                bLf[ni] = frag_ld(smem, BsL, row, kb);
            }
#pragma unroll
            for (int mi = 0; mi < 4; ++mi)
#pragma unroll
                for (int ni = 0; ni < 4; ++ni) {
                    acc[mi][ni] = __builtin_amdgcn_mfma_f32_16x16x32_bf16(aHf[mi], bHf[ni], acc[mi][ni], 0, 0, 0);
                    acc[mi][ni] = __builtin_amdgcn_mfma_f32_16x16x32_bf16(aHf[mi], bLf[ni], acc[mi][ni], 0, 0, 0);
                    acc[mi][ni] = __builtin_amdgcn_mfma_f32_16x16x32_bf16(aLf[mi], bHf[ni], acc[mi][ni], 0, 0, 0);
                }
        }
    }
    __syncthreads();                      // all frag reads done; reuse smem as z
    float (*z)[128] = (float(*)[128])smem;
#pragma unroll
    for (int mi = 0; mi < 4; ++mi)
#pragma unroll
        for (int ni = 0; ni < 4; ++ni)
#pragma unroll
            for (int r = 0; r < 4; ++r) {
                int m = wr * 64 + mi * 16 + (lane >> 4) * 4 + r;
                int n = wc * 64 + ni * 16 + (lane & 15);
                z[m][n] = acc[mi][ni][r];
            }
    __syncthreads();
    // epilogue: n-tile covers 32 h-cols x 4 gates (gate-stride 32 via W reorder)
    const int cu = tid & 31;
    const int rg = tid >> 5;              // 0..7
    const int j  = blockIdx.y * 32 + cu;
    const float bi = bsum[0 * NH + j], bfv = bsum[1 * NH + j];
    const float bg = bsum[2 * NH + j], bo  = bsum[3 * NH + j];
#pragma unroll
    for (int it = 0; it < 16; ++it) {
        int m = rg * 16 + it;
        size_t idx = (size_t)(b0 + m) * NH + j;
        float zi = z[m][cu]      + bi;
        float zf = z[m][32 + cu] + bfv;
        float zg = z[m][64 + cu] + bg;
        float zo = z[m][96 + cu] + bo;
        float iv = 1.f / (1.f + expf(-zi));
        float fv = 1.f / (1.f + expf(-zf));
        float gv = tanhf(zg);
        float ov = 1.f / (1.f + expf(-zo));
        float cv = fv * cc[idx] + iv * gv;
        cc[idx] = cv;
        float av = ov * tanhf(cv);
        unsigned short ah = f2bf_rne(av);
        aH[idx] = ah;
        aL[idx] = f2bf_rne(av - bf2f(ah));
    }
}

// ---------------- GEMM2: h_new = a @ Whr^T. Tile 64(b) x 64(d), K=512, 3-term.
// grid (32, 4) = 128 blocks, 4 waves of 32x32 each.
template <bool STAGED>
__global__ __launch_bounds__(256) void recur_mfma(
    const unsigned short* __restrict__ aH, const unsigned short* __restrict__ aL,
    const unsigned short* __restrict__ WhrHp, const unsigned short* __restrict__ WhrLp,
    unsigned short* __restrict__ hH, unsigned short* __restrict__ hL,
    float* __restrict__ hseq, float* __restrict__ out, int t)
{
    __shared__ char smem[32768];
    constexpr int AsH = 0, AsL = 8192, BsH = 16384, BsL = 24576;

    const int tid  = threadIdx.x;
    const int lane = tid & 63;
    const int wave = tid >> 6;
    const int wr = wave >> 1, wc = wave & 1;
    const int b0 = blockIdx.x * 64;
    const int d0 = blockIdx.y * 64;

    f32x4 acc[2][2];
#pragma unroll
    for (int mi = 0; mi < 2; ++mi)
#pragma unroll
        for (int ni = 0; ni < 2; ++ni)
            acc[mi][ni] = f32x4{0.f, 0.f, 0.f, 0.f};

    const int lrow = lane & 15;
    const int lk   = (lane >> 4) * 16;

    for (int ch = 0; ch < 8; ++ch) {
        __syncthreads();
        stage_tile<64>(aH,    b0, NH, ch * 64, smem, AsH, wave, lane);
        stage_tile<64>(aL,    b0, NH, ch * 64, smem, AsL, wave, lane);
        stage_tile<64>(WhrHp, d0, NH, ch * 64, smem, BsH, wave, lane);
        stage_tile<64>(WhrLp, d0, NH, ch * 64, smem, BsL, wave, lane);
        __syncthreads();
#pragma unroll
        for (int kk = 0; kk < 2; ++kk) {
            const int kb = kk * 64 + lk;
            bf16x8 aHf[2], aLf[2], bHf[2], bLf[2];
#pragma unroll
            for (int mi = 0; mi < 2; ++mi) {
                int row = wr * 32 + mi * 16 + lrow;
                aHf[mi] = frag_ld(smem, AsH, row, kb);
                aLf[mi] = frag_ld(smem, AsL, row, kb);
            }
#pragma unroll
            for (int ni = 0; ni < 2; ++ni) {
                int row = wc * 32 + ni * 16 + lrow;
                bHf[ni] = frag_ld(smem, BsH, row, kb);
                bLf[ni] = frag_ld(smem, BsL, row, kb);
            }
#pragma unroll
            for (int mi = 0; mi < 2; ++mi)
#pragma unroll
                for (int ni = 0; ni < 2; ++ni) {
                    acc[mi][ni] = __builtin_amdgcn_mfma_f32_16x16x32_bf16(aHf[mi], bHf[ni], acc[mi][ni], 0, 0, 0);
                    acc[mi][ni] = __builtin_amdgcn_mfma_f32_16x16x32_bf16(aHf[mi], bLf[ni], acc[mi][ni], 0, 0, 0);
                    acc[mi][ni] = __builtin_amdgcn_mfma_f32_16x16x32_bf16(aLf[mi], bHf[ni], acc[mi][ni], 0, 0, 0);
                }
        }
    }
    // epilogue straight from accumulators
#pragma unroll
    for (int mi = 0; mi < 2; ++mi)
#pragma unroll
        for (int ni = 0; ni < 2; ++ni)
#pragma unroll
            for (int r = 0; r < 4; ++r) {
                int b = b0 + wr * 32 + mi * 16 + (lane >> 4) * 4 + r;
                int d = d0 + wc * 32 + ni * 16 + (lane & 15);
                float v = acc[mi][ni][r];
                if (STAGED) hseq[((size_t)t * NB + b) * ND + d] = v;
                else        out[((size_t)b * ND + d) * NT + t]  = v;
                size_t hidx = (size_t)b * ND + d;
                unsigned short hh = f2bf_rne(v);
                hH[hidx] = hh;
                hL[hidx] = f2bf_rne(v - bf2f(hh));
            }
}

// ---------------- final transpose: hseq (t,b,d) -> out (b,d,t)
__global__ __launch_bounds__(256) void transpose_kernel(
    const float* __restrict__ hseq, float* __restrict__ out) {
    __shared__ float tile[64][65];
    const int tid = threadIdx.x;
    const int d0  = blockIdx.x * 64;
    const int b   = blockIdx.y;
    const int x   = tid & 63;
    const int y   = tid >> 6;  // 0..3
#pragma unroll
    for (int r = 0; r < 16; ++r) {
        int t = y + r * 4;
        tile[t][x] = hseq[((size_t)t * NB + b) * ND + d0 + x];
    }
    __syncthreads();
#pragma unroll
    for (int r = 0; r < 16; ++r) {
        int d = y + r * 4;
        out[((size_t)b * ND + d0 + d) * NT + x] = tile[x][d];
    }
}

extern "C" void kernel_launch(void* const* d_in, const int* in_sizes, int n_in,
                              void* d_out, int out_size, void* d_ws, size_t ws_size,
                              hipStream_t stream) {
    const float* c   = (const float*)d_in[0];
    const float* Wih = (const float*)d_in[1];
    const float* Whh = (const float*)d_in[2];
    const float* bih = (const float*)d_in[3];
    const float* bhh = (const float*)d_in[4];
    const float* Whr = (const float*)d_in[5];
    float* out = (float*)d_out;

    char* ws = (char*)d_ws;
    size_t off = 0;
    auto alloc = [&](size_t bytes) -> char* {
        char* p = ws + off;
        off = (off + bytes + 255) & ~(size_t)255;
        return p;
    };
    float*          cc    = (float*)alloc((size_t)NB * NH * 4);
    float*          bsum  = (float*)alloc((size_t)N4H * 4);
    unsigned short* WrHp  = (unsigned short*)alloc((size_t)N4H * ND * 2);
    unsigned short* WrLp  = (unsigned short*)alloc((size_t)N4H * ND * 2);
    unsigned short* WhrHp = (unsigned short*)alloc((size_t)ND * NH * 2);
    unsigned short* WhrLp = (unsigned short*)alloc((size_t)ND * NH * 2);
    unsigned short* hH    = (unsigned short*)alloc((size_t)NB * ND * 2);
    unsigned short* hL    = (unsigned short*)alloc((size_t)NB * ND * 2);
    unsigned short* aH    = (unsigned short*)alloc((size_t)NB * NH * 2);
    unsigned short* aL    = (unsigned short*)alloc((size_t)NB * NH * 2);
    size_t hseq_bytes = (size_t)NT * NB * ND * 4;
    float* hseq = (float*)(ws + off);
    const bool staged = (off + hseq_bytes) <= ws_size;

    prep_kernel<<<(NB * NH) / 256, 256, 0, stream>>>(
        c, Wih, Whh, bih, bhh, Whr, cc, bsum, WrHp, WrLp, WhrHp, WhrLp, hH, hL);

    dim3 g1(NB / 128, N4H / 128);  // 16 x 16 = 256 blocks
    dim3 g2(NB / 64, ND / 64);     // 32 x 4  = 128 blocks
    for (int t = 0; t < NT; ++t) {
        gates_mfma<<<g1, 256, 0, stream>>>(hH, hL, WrHp, WrLp, bsum, cc, aH, aL);
        if (staged)
            recur_mfma<true><<<g2, 256, 0, stream>>>(aH, aL, WhrHp, WhrLp,
                                                     hH, hL, hseq, out, t);
        else
            recur_mfma<false><<<g2, 256, 0, stream>>>(aH, aL, WhrHp, WhrLp,
                                                      hH, hL, hseq, out, t);
    }
    if (staged) {
        dim3 gt(ND / 64, NB);
        transpose_kernel<<<gt, 256, 0, stream>>>(hseq, out);
    }
}

// Round 9
// 1504.474 us; speedup vs baseline: 1.7679x; 1.3360x over previous
//
#include <hip/hip_runtime.h>
#include <cstdint>
#include <cstddef>

// (B, H, D, STEP) = (2048, 512, 256, 64)
constexpr int NB  = 2048;
constexpr int NH  = 512;
constexpr int ND  = 256;
constexpr int NT  = 64;
constexpr int N4H = 2048;

typedef __attribute__((ext_vector_type(8))) __bf16 bf16x8;
typedef __attribute__((ext_vector_type(4))) float  f32x4;

__device__ inline unsigned short f2bf_rne(float f) {
    unsigned u = __builtin_bit_cast(unsigned, f);
    unsigned r = (u + 0x7FFFu + ((u >> 16) & 1u)) >> 16;
    return (unsigned short)r;
}
__device__ inline float bf2f(unsigned short h) {
    unsigned u = ((unsigned)h) << 16;
    return __builtin_bit_cast(float, u);
}

// ---------------- prep: combine weights, split bf16 hi/lo, reorder Wsum rows,
// init cc from c, zero h.
__global__ __launch_bounds__(256) void prep_kernel(
    const float* __restrict__ c,   const float* __restrict__ Wih,
    const float* __restrict__ Whh, const float* __restrict__ bih,
    const float* __restrict__ bhh, const float* __restrict__ Whr,
    float* __restrict__ cc, float* __restrict__ bsum,
    unsigned short* __restrict__ WrH,  unsigned short* __restrict__ WrL,
    unsigned short* __restrict__ WhrH, unsigned short* __restrict__ WhrL,
    unsigned short* __restrict__ hH,   unsigned short* __restrict__ hL)
{
    int i = blockIdx.x * 256 + threadIdx.x;        // 0 .. NB*NH-1 (1M)
    cc[i] = c[i];                                  // c is (B,H,1) contiguous
    if (i < N4H) bsum[i] = bih[i] + bhh[i];
    if (i < N4H * ND) {                            // Wr reorder+split; h zero
        int np = i >> 8, k = i & 255;
        int jg = np >> 7, r = np & 127, g = r >> 5, cu = r & 31;
        int src = (g * NH + jg * 32 + cu) * ND + k;
        float w = Wih[src] + Whh[src];
        unsigned short hi = f2bf_rne(w);
        WrH[i] = hi; WrL[i] = f2bf_rne(w - bf2f(hi));
        hH[i] = 0; hL[i] = 0;                      // NB*ND == N4H*ND
    }
    if (i < ND * NH) {                             // Whr split ([256][512])
        float w = Whr[i];
        unsigned short hi = f2bf_rne(w);
        WhrH[i] = hi; WhrL[i] = f2bf_rne(w - bf2f(hi));
    }
}

// ---- stage one ROWSx64-elem bf16 tile into LDS via global_load_lds width 16.
// LDS dest: linear, wave-uniform base + lane*16. Global src: per-lane, pre-swizzled
// (kb ^ ((row&7)<<4)) so swizzled ds_reads see logical data (rule #21).
template <int ROWS>
__device__ __forceinline__ void stage_tile(const unsigned short* __restrict__ g,
                                           int row0, int ldgElems, int k0Elems,
                                           char* smem, int ldsOff, int wave, int lane)
{
    constexpr int QN = ROWS / 32;                       // 1KB per q per wave
#pragma unroll
    for (int q = 0; q < QN; ++q) {
        int L   = wave * (ROWS * 32) + q * 1024 + lane * 16;  // tile-local byte off
        int row = L >> 7;
        int kb  = L & 127;
        int kbs = kb ^ ((row & 7) << 4);
        const char* src = (const char*)g +
            (size_t)(row0 + row) * (ldgElems * 2) + k0Elems * 2 + kbs;
        char* dst = smem + ldsOff + wave * (ROWS * 32) + q * 1024;  // wave-uniform
        __builtin_amdgcn_global_load_lds(
            (const __attribute__((address_space(1))) unsigned int*)src,
            (__attribute__((address_space(3))) unsigned int*)dst,
            16, 0, 0);
    }
}

__device__ __forceinline__ bf16x8 frag_ld(const char* smem, int off, int row, int kb) {
    int kbs = kb ^ ((row & 7) << 4);
    return *(const bf16x8*)(smem + off + row * 128 + kbs);
}

// ---------------- gates: z = h @ WrT (+bias), gates, cc update, a out (bf16 hi/lo).
// Tile 64(b) x 128(n'), K=256, 3-term split. grid (NB/64, N4H/128) = (32,16) = 512
// blocks, 48KB LDS -> 2 blocks/CU (8 waves/CU) for staging-latency overlap.
__global__ __launch_bounds__(256) void gates_step(
    const unsigned short* __restrict__ hH, const unsigned short* __restrict__ hL,
    const unsigned short* __restrict__ WrH, const unsigned short* __restrict__ WrL,
    const float* __restrict__ bsum, float* __restrict__ cc,
    unsigned short* __restrict__ aH, unsigned short* __restrict__ aL)
{
    __shared__ char smem[49152];
    constexpr int AsH = 0, AsL = 8192, BsH = 16384, BsL = 32768;

    const int tid  = threadIdx.x;
    const int lane = tid & 63;
    const int wave = tid >> 6;
    const int wr = wave >> 1, wc = wave & 1;   // 2x2 waves of 32(b) x 64(n)
    const int b0 = blockIdx.x * 64;
    const int ny = blockIdx.y;
    const int n0 = ny * 128;

    f32x4 acc[2][4];
#pragma unroll
    for (int mi = 0; mi < 2; ++mi)
#pragma unroll
        for (int ni = 0; ni < 4; ++ni)
            acc[mi][ni] = f32x4{0.f, 0.f, 0.f, 0.f};

    const int lrow = lane & 15;
    const int lk   = (lane >> 4) * 16;    // k-group byte offset

#pragma unroll 1
    for (int ch = 0; ch < 4; ++ch) {
        __syncthreads();
        stage_tile<64> (hH,  b0, ND, ch * 64, smem, AsH, wave, lane);
        stage_tile<64> (hL,  b0, ND, ch * 64, smem, AsL, wave, lane);
        stage_tile<128>(WrH, n0, ND, ch * 64, smem, BsH, wave, lane);
        stage_tile<128>(WrL, n0, ND, ch * 64, smem, BsL, wave, lane);
        __syncthreads();
#pragma unroll
        for (int kk = 0; kk < 2; ++kk) {
            const int kb = kk * 64 + lk;
            bf16x8 aHf[2], aLf[2], bHf[4], bLf[4];
#pragma unroll
            for (int mi = 0; mi < 2; ++mi) {
                int row = wr * 32 + mi * 16 + lrow;
                aHf[mi] = frag_ld(smem, AsH, row, kb);
                aLf[mi] = frag_ld(smem, AsL, row, kb);
            }
#pragma unroll
            for (int ni = 0; ni < 4; ++ni) {
                int row = wc * 64 + ni * 16 + lrow;
                bHf[ni] = frag_ld(smem, BsH, row, kb);
                bLf[ni] = frag_ld(smem, BsL, row, kb);
            }
#pragma unroll
            for (int mi = 0; mi < 2; ++mi)
#pragma unroll
                for (int ni = 0; ni < 4; ++ni) {
                    acc[mi][ni] = __builtin_amdgcn_mfma_f32_16x16x32_bf16(aHf[mi], bHf[ni], acc[mi][ni], 0, 0, 0);
                    acc[mi][ni] = __builtin_amdgcn_mfma_f32_16x16x32_bf16(aHf[mi], bLf[ni], acc[mi][ni], 0, 0, 0);
                    acc[mi][ni] = __builtin_amdgcn_mfma_f32_16x16x32_bf16(aLf[mi], bHf[ni], acc[mi][ni], 0, 0, 0);
                }
        }
    }
    __syncthreads();                      // frag reads done; reuse smem as z
    float (*z)[128] = (float(*)[128])smem;
#pragma unroll
    for (int mi = 0; mi < 2; ++mi)
#pragma unroll
        for (int ni = 0; ni < 4; ++ni)
#pragma unroll
            for (int r = 0; r < 4; ++r) {
                int m = wr * 32 + mi * 16 + (lane >> 4) * 4 + r;
                int n = wc * 64 + ni * 16 + (lane & 15);
                z[m][n] = acc[mi][ni][r];
            }
    __syncthreads();
    // epilogue: n-tile covers 32 h-cols x 4 gates (gate-stride 32 via W reorder)
    const int cu = tid & 31;
    const int rg = tid >> 5;              // 0..7
    const int j  = ny * 32 + cu;
    const float bi = bsum[0 * NH + j], bfv = bsum[1 * NH + j];
    const float bg = bsum[2 * NH + j], bo  = bsum[3 * NH + j];
#pragma unroll
    for (int it = 0; it < 8; ++it) {
        int m = rg * 8 + it;
        size_t idx = (size_t)(b0 + m) * NH + j;
        float zi = z[m][cu]      + bi;
        float zf = z[m][32 + cu] + bfv;
        float zg = z[m][64 + cu] + bg;
        float zo = z[m][96 + cu] + bo;
        float iv = 1.f / (1.f + expf(-zi));
        float fv = 1.f / (1.f + expf(-zf));
        float gv = tanhf(zg);
        float ov = 1.f / (1.f + expf(-zo));
        float cv = fv * cc[idx] + iv * gv;
        cc[idx] = cv;
        float av = ov * tanhf(cv);
        unsigned short ah = f2bf_rne(av);
        aH[idx] = ah;
        aL[idx] = f2bf_rne(av - bf2f(ah));
    }
}

// ---------------- recur: h_new = a @ Whr^T. Tile 32(b) x 32(d), K=512, 3-term.
// grid (NB/32, ND/32) = (64,8) = 512 blocks, 16KB LDS -> 2+ blocks/CU.
// 4 waves 2x2, each 16x16 output.
template <bool STAGED>
__global__ __launch_bounds__(256) void recur_step(
    const unsigned short* __restrict__ aH, const unsigned short* __restrict__ aL,
    const unsigned short* __restrict__ WhrHp, const unsigned short* __restrict__ WhrLp,
    unsigned short* __restrict__ hH, unsigned short* __restrict__ hL,
    float* __restrict__ hseq, float* __restrict__ out, int t)
{
    __shared__ char smem[16384];
    constexpr int AsH = 0, AsL = 4096, BsH = 8192, BsL = 12288;

    const int tid  = threadIdx.x;
    const int lane = tid & 63;
    const int wave = tid >> 6;
    const int wr = wave >> 1, wc = wave & 1;
    const int b0 = blockIdx.x * 32;
    const int d0 = blockIdx.y * 32;

    f32x4 acc = f32x4{0.f, 0.f, 0.f, 0.f};

    const int lrow = lane & 15;
    const int lk   = (lane >> 4) * 16;

#pragma unroll 1
    for (int ch = 0; ch < 8; ++ch) {
        __syncthreads();
        stage_tile<32>(aH,    b0, NH, ch * 64, smem, AsH, wave, lane);
        stage_tile<32>(aL,    b0, NH, ch * 64, smem, AsL, wave, lane);
        stage_tile<32>(WhrHp, d0, NH, ch * 64, smem, BsH, wave, lane);
        stage_tile<32>(WhrLp, d0, NH, ch * 64, smem, BsL, wave, lane);
        __syncthreads();
#pragma unroll
        for (int kk = 0; kk < 2; ++kk) {
            const int kb = kk * 64 + lk;
            int arow = wr * 16 + lrow;
            int brow = wc * 16 + lrow;
            bf16x8 aHf = frag_ld(smem, AsH, arow, kb);
            bf16x8 aLf = frag_ld(smem, AsL, arow, kb);
            bf16x8 bHf = frag_ld(smem, BsH, brow, kb);
            bf16x8 bLf = frag_ld(smem, BsL, brow, kb);
            acc = __builtin_amdgcn_mfma_f32_16x16x32_bf16(aHf, bHf, acc, 0, 0, 0);
            acc = __builtin_amdgcn_mfma_f32_16x16x32_bf16(aHf, bLf, acc, 0, 0, 0);
            acc = __builtin_amdgcn_mfma_f32_16x16x32_bf16(aLf, bHf, acc, 0, 0, 0);
        }
    }
#pragma unroll
    for (int r = 0; r < 4; ++r) {
        int b = b0 + wr * 16 + (lane >> 4) * 4 + r;
        int d = d0 + wc * 16 + (lane & 15);
        float v = acc[r];
        if (STAGED) hseq[((size_t)t * NB + b) * ND + d] = v;
        else        out[((size_t)b * ND + d) * NT + t]  = v;
        size_t hidx = (size_t)b * ND + d;
        unsigned short hh = f2bf_rne(v);
        hH[hidx] = hh;
        hL[hidx] = f2bf_rne(v - bf2f(hh));
    }
}

// ---------------- final transpose: hseq (t,b,d) -> out (b,d,t)
__global__ __launch_bounds__(256) void transpose_kernel(
    const float* __restrict__ hseq, float* __restrict__ out) {
    __shared__ float tile[64][65];
    const int tid = threadIdx.x;
    const int d0  = blockIdx.x * 64;
    const int b   = blockIdx.y;
    const int x   = tid & 63;
    const int y   = tid >> 6;  // 0..3
#pragma unroll
    for (int r = 0; r < 16; ++r) {
        int t = y + r * 4;
        tile[t][x] = hseq[((size_t)t * NB + b) * ND + d0 + x];
    }
    __syncthreads();
#pragma unroll
    for (int r = 0; r < 16; ++r) {
        int d = y + r * 4;
        out[((size_t)b * ND + d0 + d) * NT + x] = tile[x][d];
    }
}

extern "C" void kernel_launch(void* const* d_in, const int* in_sizes, int n_in,
                              void* d_out, int out_size, void* d_ws, size_t ws_size,
                              hipStream_t stream) {
    const float* c   = (const float*)d_in[0];
    const float* Wih = (const float*)d_in[1];
    const float* Whh = (const float*)d_in[2];
    const float* bih = (const float*)d_in[3];
    const float* bhh = (const float*)d_in[4];
    const float* Whr = (const float*)d_in[5];
    float* out = (float*)d_out;

    char* ws = (char*)d_ws;
    size_t off = 0;
    auto alloc = [&](size_t bytes) -> char* {
        char* p = ws + off;
        off = (off + bytes + 255) & ~(size_t)255;
        return p;
    };
    float*          cc    = (float*)alloc((size_t)NB * NH * 4);
    float*          bsum  = (float*)alloc((size_t)N4H * 4);
    unsigned short* WrHp  = (unsigned short*)alloc((size_t)N4H * ND * 2);
    unsigned short* WrLp  = (unsigned short*)alloc((size_t)N4H * ND * 2);
    unsigned short* WhrHp = (unsigned short*)alloc((size_t)ND * NH * 2);
    unsigned short* WhrLp = (unsigned short*)alloc((size_t)ND * NH * 2);
    unsigned short* hH    = (unsigned short*)alloc((size_t)NB * ND * 2);
    unsigned short* hL    = (unsigned short*)alloc((size_t)NB * ND * 2);
    unsigned short* aH    = (unsigned short*)alloc((size_t)NB * NH * 2);
    unsigned short* aL    = (unsigned short*)alloc((size_t)NB * NH * 2);
    size_t hseq_bytes = (size_t)NT * NB * ND * 4;
    float* hseq = (float*)(ws + off);
    const bool staged = (off + hseq_bytes) <= ws_size;

    prep_kernel<<<(NB * NH) / 256, 256, 0, stream>>>(
        c, Wih, Whh, bih, bhh, Whr, cc, bsum, WrHp, WrLp, WhrHp, WhrLp, hH, hL);

    dim3 g1(NB / 64, N4H / 128);   // (32,16) = 512 blocks
    dim3 g2(NB / 32, ND / 32);     // (64,8)  = 512 blocks
    for (int t = 0; t < NT; ++t) {
        gates_step<<<g1, 256, 0, stream>>>(hH, hL, WrHp, WrLp, bsum, cc, aH, aL);
        if (staged)
            recur_step<true><<<g2, 256, 0, stream>>>(aH, aL, WhrHp, WhrLp,
                                                     hH, hL, hseq, out, t);
        else
            recur_step<false><<<g2, 256, 0, stream>>>(aH, aL, WhrHp, WhrLp,
                                                      hH, hL, hseq, out, t);
    }
    if (staged) {
        dim3 gt(ND / 64, NB);
        transpose_kernel<<<gt, 256, 0, stream>>>(hseq, out);
    }
}